// Round 3
// baseline (1544.619 us; speedup 1.0000x reference)
//
#include <hip/hip_runtime.h>

#define NN 500000
#define CC 256
#define BB 512

typedef __attribute__((ext_vector_type(8))) short short8v;
typedef __attribute__((ext_vector_type(4))) float f32x4;

__device__ __forceinline__ unsigned short f2bf_u(float f){
  unsigned u = __float_as_uint(f);
  unsigned r = u + 0x7FFFu + ((u>>16)&1u);   // round-to-nearest-even
  return (unsigned short)(r>>16);
}
__device__ __forceinline__ float bf2f(unsigned short h){
  return __uint_as_float(((unsigned)h)<<16);
}
__device__ __forceinline__ float gelu_f(float v){
  return 0.5f*v*(1.0f + erff(v*0.70710678118654752f));  // exact GELU
}
// order-preserving float<->uint encoding for atomicMax on floats
__device__ __forceinline__ unsigned encf(float f){
  unsigned u = __float_as_uint(f);
  return (u & 0x80000000u) ? ~u : (u | 0x80000000u);
}
__device__ __forceinline__ float decf(unsigned u){
  return (u & 0x80000000u) ? __uint_as_float(u & 0x7fffffffu) : __uint_as_float(~u);
}

// ---------------- pass 0: question MLP (tiny) ----------------
__global__ void qmlp_k(const float* __restrict__ u, const float* __restrict__ Wq1,
                       const float* __restrict__ bq1, const float* __restrict__ Wq2,
                       const float* __restrict__ bq2, float* __restrict__ q){
  __shared__ float us[256];
  __shared__ float hs[256];
  const int row = blockIdx.x, c = threadIdx.x;
  us[c] = u[row*256 + c];
  __syncthreads();
  float s = bq1[c];
  #pragma unroll 4
  for (int k=0;k<256;k++) s = fmaf(us[k], Wq1[k*256+c], s);
  hs[c] = gelu_f(s);
  __syncthreads();
  float s2 = bq2[c];
  #pragma unroll 4
  for (int k=0;k<256;k++) s2 = fmaf(hs[k], Wq2[k*256+c], s2);
  q[row*256+c] = s2;
}

// ---------------- pass 0: weight transpose + bf16 convert ----------------
__global__ void wtrans_k(const float* __restrict__ Wn1, const float* __restrict__ Wn2,
                         unsigned short* __restrict__ W1T, unsigned short* __restrict__ W2T){
  const float* W = blockIdx.y ? Wn2 : Wn1;
  unsigned short* T = blockIdx.y ? W2T : W1T;
  const int k = blockIdx.x, c = threadIdx.x;
  T[c*256 + k] = f2bf_u(W[k*256 + c]);   // WT[col][k]
}

// ---------------- big GEMMs: tile 64 rows x 256 cols, BK=64, 4 waves ----------------
// PASS 1: h = GELU(x @ Wn1 + bn1)            (A = x fp32, converted while staging)
// PASS 2: xn = h @ Wn2 + bn2 (in-place), plus fused gate partial = (xn . q[batch])/16
template<int PASS>
__global__ void __launch_bounds__(256)
mlp_gemm(const float* __restrict__ xin, const unsigned short* __restrict__ hin,
         const unsigned short* __restrict__ WT, const float* __restrict__ bias,
         unsigned short* __restrict__ hout, const float* __restrict__ q,
         const int* __restrict__ batch, float* __restrict__ gate){
  __shared__ unsigned short Ald[64*64];    // [row][k]   8 KB
  __shared__ unsigned short Bld[256*64];   // [col][k]  32 KB
  const int t = threadIdx.x;
  const int bid = blockIdx.x;
  const int rowbase = bid*64;
  const int w = t>>6, l = t&63;
  const int lg = l>>4, li = l&15;
  const int wc = w;                        // wave owns 64-col panel

  f32x4 acc[4][4];
  const f32x4 zero = {0.f,0.f,0.f,0.f};
  #pragma unroll
  for (int m=0;m<4;m++)
    #pragma unroll
    for (int n=0;n<4;n++) acc[m][n] = zero;

  const int arow = t>>2, acq = t&3;        // A: 64 rows x 4 chunks of 16
  int gr = rowbase + arow; if (gr >= NN) gr = NN-1;   // clamp stays in own block's rows

  for (int kk=0; kk<256; kk+=64){
    // ---- stage A ----
    if (PASS==1){
      const float4* src = (const float4*)(xin + (size_t)gr*256 + kk + acq*16);
      float4 f0=src[0], f1=src[1], f2=src[2], f3=src[3];
      uint4 o0, o1;
      o0.x = (unsigned)f2bf_u(f0.x) | ((unsigned)f2bf_u(f0.y)<<16);
      o0.y = (unsigned)f2bf_u(f0.z) | ((unsigned)f2bf_u(f0.w)<<16);
      o0.z = (unsigned)f2bf_u(f1.x) | ((unsigned)f2bf_u(f1.y)<<16);
      o0.w = (unsigned)f2bf_u(f1.z) | ((unsigned)f2bf_u(f1.w)<<16);
      o1.x = (unsigned)f2bf_u(f2.x) | ((unsigned)f2bf_u(f2.y)<<16);
      o1.y = (unsigned)f2bf_u(f2.z) | ((unsigned)f2bf_u(f2.w)<<16);
      o1.z = (unsigned)f2bf_u(f3.x) | ((unsigned)f2bf_u(f3.y)<<16);
      o1.w = (unsigned)f2bf_u(f3.z) | ((unsigned)f2bf_u(f3.w)<<16);
      uint4* dst = (uint4*)(Ald + arow*64 + acq*16);
      dst[0]=o0; dst[1]=o1;
    } else {
      const uint4* src = (const uint4*)(hin + (size_t)gr*256 + kk + acq*16);
      uint4 v0=src[0], v1=src[1];
      uint4* dst = (uint4*)(Ald + arow*64 + acq*16);
      dst[0]=v0; dst[1]=v1;
    }
    // ---- stage B: thread t copies col t's 64 k-elems (128 B) ----
    {
      const uint4* src = (const uint4*)(WT + (size_t)t*256 + kk);
      uint4* dst = (uint4*)(Bld + t*64);
      #pragma unroll
      for (int i=0;i<8;i++) dst[i] = src[i];
    }
    __syncthreads();
    const unsigned short* ab = Ald + li*64 + lg*8;
    const unsigned short* bb = Bld + (wc*64 + li)*64 + lg*8;
    #pragma unroll
    for (int ks=0; ks<64; ks+=32){
      short8v a[4], b[4];
      #pragma unroll
      for (int m=0;m<4;m++) a[m] = *(const short8v*)(ab + m*1024 + ks);
      #pragma unroll
      for (int n=0;n<4;n++) b[n] = *(const short8v*)(bb + n*1024 + ks);
      #pragma unroll
      for (int m=0;m<4;m++)
        #pragma unroll
        for (int n=0;n<4;n++)
          acc[m][n] = __builtin_amdgcn_mfma_f32_16x16x32_bf16(a[m], b[n], acc[m][n], 0, 0, 0);
    }
    __syncthreads();
  }

  // ---- epilogue ----  C/D frag: col = li, row = lg*4 + reg   [m91-verified]
  if (PASS==1){
    #pragma unroll
    for (int m=0;m<4;m++){
      #pragma unroll
      for (int n=0;n<4;n++){
        const int gcol = wc*64 + n*16 + li;
        const float bs = bias[gcol];
        f32x4 v = acc[m][n];
        #pragma unroll
        for (int r=0;r<4;r++){
          const int grow = rowbase + m*16 + lg*4 + r;
          if (grow < NN)
            hout[(size_t)grow*256 + gcol] = f2bf_u(gelu_f(v[r]+bs));
        }
      }
    }
  } else {
    #pragma unroll
    for (int m=0;m<4;m++){
      int grows[4], bsg[4];
      #pragma unroll
      for (int r=0;r<4;r++){
        grows[r] = rowbase + m*16 + lg*4 + r;
        bsg[r] = (grows[r] < NN) ? batch[grows[r]] : 0;
      }
      float p[4] = {0.f,0.f,0.f,0.f};
      #pragma unroll
      for (int n=0;n<4;n++){
        const int gcol = wc*64 + n*16 + li;
        const float bs = bias[gcol];
        f32x4 v = acc[m][n];
        #pragma unroll
        for (int r=0;r<4;r++){
          if (grows[r] < NN){
            const float val = v[r] + bs;
            hout[(size_t)grows[r]*256 + gcol] = f2bf_u(val);   // xn (in-place over h)
            p[r] = fmaf(val, q[bsg[r]*256 + gcol], p[r]);
          }
        }
      }
      #pragma unroll
      for (int r=0;r<4;r++){
        float pr = p[r];                   // reduce across the 16 lanes of this row
        pr += __shfl_xor(pr, 1);
        pr += __shfl_xor(pr, 2);
        pr += __shfl_xor(pr, 4);
        pr += __shfl_xor(pr, 8);
        if (li==0 && grows[r] < NN) atomicAdd(gate + grows[r], pr*0.0625f);  // /sqrt(256)
      }
    }
  }
}

// ---------------- segment softmax (batch is sorted) ----------------
__global__ void segmax_k(const float* __restrict__ gate, const int* __restrict__ batch,
                         unsigned* __restrict__ menc){
  const int i = blockIdx.x*512 + threadIdx.x;
  const bool ok = i < NN;
  const int b = ok ? batch[i] : batch[NN-1];
  unsigned e = encf(ok ? gate[i] : -3.4e38f);
  const int b0 = __shfl(b, 0), b63 = __shfl(b, 63);
  if (b0 == b63){
    #pragma unroll
    for (int off=32; off; off>>=1){ unsigned o = __shfl_xor(e, off); e = e > o ? e : o; }
    if ((threadIdx.x & 63) == 0) atomicMax(menc + b, e);
  } else {
    atomicMax(menc + b, e);
  }
}

__global__ void expden_k(float* __restrict__ gate, const int* __restrict__ batch,
                         const unsigned* __restrict__ menc, float* __restrict__ denom){
  const int i = blockIdx.x*512 + threadIdx.x;
  const bool ok = i < NN;
  const int b = ok ? batch[i] : batch[NN-1];
  const float mm = decf(menc[b]);
  float e = ok ? expf(gate[i] - mm) : 0.f;
  if (ok) gate[i] = e;
  const int b0 = __shfl(b, 0), b63 = __shfl(b, 63);
  if (b0 == b63){
    float s = e;
    #pragma unroll
    for (int off=32; off; off>>=1) s += __shfl_xor(s, off);
    if ((threadIdx.x & 63) == 0) atomicAdd(denom + b, s);
  } else {
    atomicAdd(denom + b, e);
  }
}

// ---------------- weighted scatter-add pooling ----------------
__global__ void pool_k(const unsigned short* __restrict__ xn, const float* __restrict__ e,
                       const float* __restrict__ denom, const int* __restrict__ batch,
                       float* __restrict__ out){
  const int wid = blockIdx.x*4 + (threadIdx.x>>6);
  const int l = threadIdx.x & 63;
  const int NW = gridDim.x*4;
  const int per = (NN + NW - 1)/NW;
  const int n0 = wid*per;
  if (n0 >= NN) return;
  int n1 = n0 + per; if (n1 > NN) n1 = NN;

  float a0=0.f, a1=0.f, a2=0.f, a3=0.f;
  int bcur = batch[n0];
  float invd = 1.0f/(denom[bcur] + 1e-16f);
  for (int n=n0; n<n1; ++n){
    const int b = batch[n];
    if (b != bcur){
      float* o = out + bcur*256 + l*4;
      atomicAdd(o+0, a0); atomicAdd(o+1, a1); atomicAdd(o+2, a2); atomicAdd(o+3, a3);
      a0=a1=a2=a3=0.f;
      bcur = b;
      invd = 1.0f/(denom[bcur] + 1e-16f);
    }
    const float wgt = e[n]*invd;
    const ushort4 xv = *(const ushort4*)(xn + (size_t)n*256 + l*4);
    a0 = fmaf(wgt, bf2f(xv.x), a0);
    a1 = fmaf(wgt, bf2f(xv.y), a1);
    a2 = fmaf(wgt, bf2f(xv.z), a2);
    a3 = fmaf(wgt, bf2f(xv.w), a3);
  }
  float* o = out + bcur*256 + l*4;
  atomicAdd(o+0, a0); atomicAdd(o+1, a1); atomicAdd(o+2, a2); atomicAdd(o+3, a3);
}

extern "C" void kernel_launch(void* const* d_in, const int* in_sizes, int n_in,
                              void* d_out, int out_size, void* d_ws, size_t ws_size,
                              hipStream_t stream){
  const float* x   = (const float*)d_in[0];
  const float* u   = (const float*)d_in[1];
  const int*  batch= (const int*)d_in[2];
  const float* Wn1 = (const float*)d_in[4];
  const float* bn1 = (const float*)d_in[5];
  const float* Wn2 = (const float*)d_in[6];
  const float* bn2 = (const float*)d_in[7];
  const float* Wq1 = (const float*)d_in[8];
  const float* bq1 = (const float*)d_in[9];
  const float* Wq2 = (const float*)d_in[10];
  const float* bq2 = (const float*)d_in[11];
  float* out = (float*)d_out;

  char* ws = (char*)d_ws;
  unsigned short* hws = (unsigned short*)ws;                 // [N][256] bf16 (h, then xn in-place)
  float* gate          = (float*)(ws + 256000000);           // [N] fp32
  float* q             = (float*)(ws + 258000000);           // [B][256] fp32
  unsigned short* W1T  = (unsigned short*)(ws + 258524288);  // [256][256] bf16 (transposed)
  unsigned short* W2T  = (unsigned short*)(ws + 258655360);
  unsigned* menc       = (unsigned*)(ws + 258786432);        // [B] encoded max
  float* denom         = (float*)(ws + 258788480);           // [B]

  hipMemsetAsync(gate, 0, (size_t)NN*4, stream);
  hipMemsetAsync(menc, 0, BB*4, stream);     // enc-space 0 < every finite float's encoding
  hipMemsetAsync(denom, 0, BB*4, stream);
  hipMemsetAsync(out, 0, (size_t)BB*CC*4, stream);

  qmlp_k<<<BB, 256, 0, stream>>>(u, Wq1, bq1, Wq2, bq2, q);
  wtrans_k<<<dim3(256,2), 256, 0, stream>>>(Wn1, Wn2, W1T, W2T);

  const int gblocks = (NN + 63)/64;   // 7813
  mlp_gemm<1><<<gblocks, 256, 0, stream>>>(x, nullptr, W1T, bn1, hws,
                                           nullptr, nullptr, nullptr);
  mlp_gemm<2><<<gblocks, 256, 0, stream>>>(nullptr, hws, W2T, bn2, hws,
                                           q, batch, gate);

  segmax_k<<<(NN+511)/512, 512, 0, stream>>>(gate, batch, menc);
  expden_k<<<(NN+511)/512, 512, 0, stream>>>(gate, batch, menc, denom);
  pool_k<<<1024, 256, 0, stream>>>(hws, gate, denom, batch, out);
}

// Round 4
// 1284.293 us; speedup vs baseline: 1.2027x; 1.2027x over previous
//
#include <hip/hip_runtime.h>

#define NN 500000
#define CC 256
#define BB 512

typedef __attribute__((ext_vector_type(8))) short short8v;
typedef __attribute__((ext_vector_type(4))) float f32x4;

__device__ __forceinline__ unsigned short f2bf_u(float f){
  unsigned u = __float_as_uint(f);
  unsigned r = u + 0x7FFFu + ((u>>16)&1u);   // round-to-nearest-even
  return (unsigned short)(r>>16);
}
__device__ __forceinline__ float bf2f(unsigned short h){
  return __uint_as_float(((unsigned)h)<<16);
}
__device__ __forceinline__ float gelu_f(float v){
  return 0.5f*v*(1.0f + erff(v*0.70710678118654752f));  // exact GELU
}
// order-preserving float<->uint encoding for atomicMax on floats
__device__ __forceinline__ unsigned encf(float f){
  unsigned u = __float_as_uint(f);
  return (u & 0x80000000u) ? ~u : (u | 0x80000000u);
}
__device__ __forceinline__ float decf(unsigned u){
  return (u & 0x80000000u) ? __uint_as_float(u & 0x7fffffffu) : __uint_as_float(~u);
}

// ---------------- pass 0: question MLP (tiny) ----------------
__global__ void qmlp_k(const float* __restrict__ u, const float* __restrict__ Wq1,
                       const float* __restrict__ bq1, const float* __restrict__ Wq2,
                       const float* __restrict__ bq2, float* __restrict__ q){
  __shared__ float us[256];
  __shared__ float hs[256];
  const int row = blockIdx.x, c = threadIdx.x;
  us[c] = u[row*256 + c];
  __syncthreads();
  float s = bq1[c];
  #pragma unroll 4
  for (int k=0;k<256;k++) s = fmaf(us[k], Wq1[k*256+c], s);
  hs[c] = gelu_f(s);
  __syncthreads();
  float s2 = bq2[c];
  #pragma unroll 4
  for (int k=0;k<256;k++) s2 = fmaf(hs[k], Wq2[k*256+c], s2);
  q[row*256+c] = s2;
}

// ---------------- pass 0: weights -> bf16, k-chunk-major Wk[kc][col][8] ----------------
// Wk short-offset(k, col) = (k>>3)*2048 + col*8 + (k&7)
__global__ void wk_k(const float* __restrict__ Wn1, const float* __restrict__ Wn2,
                     unsigned short* __restrict__ Wk1, unsigned short* __restrict__ Wk2){
  const float* W = blockIdx.y ? Wn2 : Wn1;
  unsigned short* T = blockIdx.y ? Wk2 : Wk1;
  const int k = blockIdx.x, c = threadIdx.x;
  T[(k>>3)*2048 + c*8 + (k&7)] = f2bf_u(W[k*256 + c]);
}

// ---------------- big GEMMs: 128 rows x 256 cols, BK=64, 8 waves ----------------
// LDS layouts are k-chunk-major (16-B granules): bank = (row&7)*4 -> even 8 dwords/bank
//   Asw[kc 0..7][row 0..127][8]  : 16 KB
//   Bsw[kc 0..7][col 0..255][8]  : 32 KB
// PASS 1: h = GELU(x @ Wn1 + bn1)           (A = x fp32, converted while staging)
// PASS 2: xn = h @ Wn2 + bn2 (in-place), plus fused gate partial = (xn . q[batch])/16
template<int PASS>
__global__ void __launch_bounds__(512, 4)
mlp_gemm(const float* __restrict__ xin, const unsigned short* hin,
         const unsigned short* __restrict__ Wk, const float* __restrict__ bias,
         unsigned short* hout, const float* __restrict__ q,
         const int* __restrict__ batch, float* __restrict__ gate){
  __shared__ unsigned short Asw[8*128*8];   // 16 KB
  __shared__ unsigned short Bsw[8*256*8];   // 32 KB
  const int t = threadIdx.x;
  const int rowbase = blockIdx.x*128;
  const int w = t>>6, l = t&63;
  const int lg = l>>4, li = l&15;
  const int wr = w>>2, wc = w&3;           // wave -> (row-half, col-panel)

  f32x4 acc[4][4];
  const f32x4 zero = {0.f,0.f,0.f,0.f};
  #pragma unroll
  for (int m=0;m<4;m++)
    #pragma unroll
    for (int n=0;n<4;n++) acc[m][n] = zero;

  // A staging: thread t -> row r=t>>2, 16-elem chunk c=t&3 (k = kk+c*16 .. +16)
  const int ar = t>>2, ac = t&3;
  int gr = rowbase + ar; if (gr >= NN) gr = NN-1;   // clamp stays within this block's rows

  for (int kk=0; kk<256; kk+=64){
    // ---- stage A -> Asw[kc=2c+j][r][8] ----
    if (PASS==1){
      const float4* src = (const float4*)(xin + (size_t)gr*256 + kk + ac*16);
      float4 f0=src[0], f1=src[1], f2=src[2], f3=src[3];
      uint4 o0, o1;
      o0.x = (unsigned)f2bf_u(f0.x) | ((unsigned)f2bf_u(f0.y)<<16);
      o0.y = (unsigned)f2bf_u(f0.z) | ((unsigned)f2bf_u(f0.w)<<16);
      o0.z = (unsigned)f2bf_u(f1.x) | ((unsigned)f2bf_u(f1.y)<<16);
      o0.w = (unsigned)f2bf_u(f1.z) | ((unsigned)f2bf_u(f1.w)<<16);
      o1.x = (unsigned)f2bf_u(f2.x) | ((unsigned)f2bf_u(f2.y)<<16);
      o1.y = (unsigned)f2bf_u(f2.z) | ((unsigned)f2bf_u(f2.w)<<16);
      o1.z = (unsigned)f2bf_u(f3.x) | ((unsigned)f2bf_u(f3.y)<<16);
      o1.w = (unsigned)f2bf_u(f3.z) | ((unsigned)f2bf_u(f3.w)<<16);
      *(uint4*)(Asw + (2*ac+0)*1024 + ar*8) = o0;
      *(uint4*)(Asw + (2*ac+1)*1024 + ar*8) = o1;
    } else {
      const uint4* src = (const uint4*)(hin + (size_t)gr*256 + kk + ac*16);
      uint4 v0=src[0], v1=src[1];
      *(uint4*)(Asw + (2*ac+0)*1024 + ar*8) = v0;
      *(uint4*)(Asw + (2*ac+1)*1024 + ar*8) = v1;
    }
    // ---- stage B: Wk region for this K-step is 32 KB contiguous, same order as Bsw ----
    {
      const unsigned short* wsrc = Wk + kk*256;       // (kk>>3)*2048 short offset
      #pragma unroll
      for (int i=0;i<4;i++){
        const int g = i*512 + t;                      // granule = kc*256 + col
        *(uint4*)(Bsw + g*8) = *(const uint4*)(wsrc + g*8);
      }
    }
    __syncthreads();
    // ---- MFMA: frag(k-slot j) = k at (ksc+lg)*8 + j ; same bijection for A and B ----
    const unsigned short* Ab = Asw + lg*1024 + (wr*64 + li)*8;
    const unsigned short* Bb = Bsw + lg*2048 + (wc*64 + li)*8;
    #pragma unroll
    for (int ksc=0; ksc<8; ksc+=4){
      short8v a[4], b[4];
      #pragma unroll
      for (int m=0;m<4;m++) a[m] = *(const short8v*)(Ab + ksc*1024 + m*128);
      #pragma unroll
      for (int n=0;n<4;n++) b[n] = *(const short8v*)(Bb + ksc*2048 + n*128);
      #pragma unroll
      for (int m=0;m<4;m++)
        #pragma unroll
        for (int n=0;n<4;n++)
          acc[m][n] = __builtin_amdgcn_mfma_f32_16x16x32_bf16(a[m], b[n], acc[m][n], 0, 0, 0);
    }
    __syncthreads();
  }

  // ---- epilogue ----  C/D frag: col = li, row = lg*4 + reg   [m91-verified]
  const int rw0 = rowbase + wr*64;
  if (PASS==1){
    #pragma unroll
    for (int m=0;m<4;m++){
      #pragma unroll
      for (int n=0;n<4;n++){
        const int gcol = wc*64 + n*16 + li;
        const float bs = bias[gcol];
        f32x4 v = acc[m][n];
        #pragma unroll
        for (int r=0;r<4;r++){
          const int grow = rw0 + m*16 + lg*4 + r;
          if (grow < NN)
            hout[(size_t)grow*256 + gcol] = f2bf_u(gelu_f(v[r]+bs));
        }
      }
    }
  } else {
    #pragma unroll
    for (int m=0;m<4;m++){
      int grows[4], bsg[4];
      #pragma unroll
      for (int r=0;r<4;r++){
        grows[r] = rw0 + m*16 + lg*4 + r;
        bsg[r] = (grows[r] < NN) ? batch[grows[r]] : 0;
      }
      float p[4] = {0.f,0.f,0.f,0.f};
      #pragma unroll
      for (int n=0;n<4;n++){
        const int gcol = wc*64 + n*16 + li;
        const float bs = bias[gcol];
        f32x4 v = acc[m][n];
        #pragma unroll
        for (int r=0;r<4;r++){
          if (grows[r] < NN){
            const float val = v[r] + bs;
            hout[(size_t)grows[r]*256 + gcol] = f2bf_u(val);   // xn (in-place over h)
            p[r] = fmaf(val, q[bsg[r]*256 + gcol], p[r]);
          }
        }
      }
      #pragma unroll
      for (int r=0;r<4;r++){
        float pr = p[r];                   // reduce across the 16 lanes of this row
        pr += __shfl_xor(pr, 1);
        pr += __shfl_xor(pr, 2);
        pr += __shfl_xor(pr, 4);
        pr += __shfl_xor(pr, 8);
        if (li==0 && grows[r] < NN) atomicAdd(gate + grows[r], pr*0.0625f);  // /sqrt(256)
      }
    }
  }
}

// ---------------- segment softmax (batch is sorted) ----------------
__global__ void segmax_k(const float* __restrict__ gate, const int* __restrict__ batch,
                         unsigned* __restrict__ menc){
  const int i = blockIdx.x*512 + threadIdx.x;
  const bool ok = i < NN;
  const int b = ok ? batch[i] : batch[NN-1];
  unsigned e = encf(ok ? gate[i] : -3.4e38f);
  const int b0 = __shfl(b, 0), b63 = __shfl(b, 63);
  if (b0 == b63){
    #pragma unroll
    for (int off=32; off; off>>=1){ unsigned o = __shfl_xor(e, off); e = e > o ? e : o; }
    if ((threadIdx.x & 63) == 0) atomicMax(menc + b, e);
  } else {
    atomicMax(menc + b, e);
  }
}

__global__ void expden_k(float* __restrict__ gate, const int* __restrict__ batch,
                         const unsigned* __restrict__ menc, float* __restrict__ denom){
  const int i = blockIdx.x*512 + threadIdx.x;
  const bool ok = i < NN;
  const int b = ok ? batch[i] : batch[NN-1];
  const float mm = decf(menc[b]);
  float e = ok ? expf(gate[i] - mm) : 0.f;
  if (ok) gate[i] = e;
  const int b0 = __shfl(b, 0), b63 = __shfl(b, 63);
  if (b0 == b63){
    float s = e;
    #pragma unroll
    for (int off=32; off; off>>=1) s += __shfl_xor(s, off);
    if ((threadIdx.x & 63) == 0) atomicAdd(denom + b, s);
  } else {
    atomicAdd(denom + b, e);
  }
}

// ---------------- weighted scatter-add pooling ----------------
__global__ void pool_k(const unsigned short* __restrict__ xn, const float* __restrict__ e,
                       const float* __restrict__ denom, const int* __restrict__ batch,
                       float* __restrict__ out){
  const int wid = blockIdx.x*4 + (threadIdx.x>>6);
  const int l = threadIdx.x & 63;
  const int NW = gridDim.x*4;
  const int per = (NN + NW - 1)/NW;
  const int n0 = wid*per;
  if (n0 >= NN) return;
  int n1 = n0 + per; if (n1 > NN) n1 = NN;

  float a0=0.f, a1=0.f, a2=0.f, a3=0.f;
  int bcur = batch[n0];
  float invd = 1.0f/(denom[bcur] + 1e-16f);
  for (int n=n0; n<n1; ++n){
    const int b = batch[n];
    if (b != bcur){
      float* o = out + bcur*256 + l*4;
      atomicAdd(o+0, a0); atomicAdd(o+1, a1); atomicAdd(o+2, a2); atomicAdd(o+3, a3);
      a0=a1=a2=a3=0.f;
      bcur = b;
      invd = 1.0f/(denom[bcur] + 1e-16f);
    }
    const float wgt = e[n]*invd;
    const ushort4 xv = *(const ushort4*)(xn + (size_t)n*256 + l*4);
    a0 = fmaf(wgt, bf2f(xv.x), a0);
    a1 = fmaf(wgt, bf2f(xv.y), a1);
    a2 = fmaf(wgt, bf2f(xv.z), a2);
    a3 = fmaf(wgt, bf2f(xv.w), a3);
  }
  float* o = out + bcur*256 + l*4;
  atomicAdd(o+0, a0); atomicAdd(o+1, a1); atomicAdd(o+2, a2); atomicAdd(o+3, a3);
}

extern "C" void kernel_launch(void* const* d_in, const int* in_sizes, int n_in,
                              void* d_out, int out_size, void* d_ws, size_t ws_size,
                              hipStream_t stream){
  const float* x   = (const float*)d_in[0];
  const float* u   = (const float*)d_in[1];
  const int*  batch= (const int*)d_in[2];
  const float* Wn1 = (const float*)d_in[4];
  const float* bn1 = (const float*)d_in[5];
  const float* Wn2 = (const float*)d_in[6];
  const float* bn2 = (const float*)d_in[7];
  const float* Wq1 = (const float*)d_in[8];
  const float* bq1 = (const float*)d_in[9];
  const float* Wq2 = (const float*)d_in[10];
  const float* bq2 = (const float*)d_in[11];
  float* out = (float*)d_out;

  char* ws = (char*)d_ws;
  unsigned short* hws = (unsigned short*)ws;                 // [N][256] bf16 (h, then xn in-place)
  float* gate          = (float*)(ws + 256000000);           // [N] fp32
  float* q             = (float*)(ws + 258000000);           // [B][256] fp32
  unsigned short* Wk1  = (unsigned short*)(ws + 258524288);  // [32][256][8] bf16 k-chunk-major
  unsigned short* Wk2  = (unsigned short*)(ws + 258655360);
  unsigned* menc       = (unsigned*)(ws + 258786432);        // [B] encoded max
  float* denom         = (float*)(ws + 258788480);           // [B]

  hipMemsetAsync(gate, 0, (size_t)NN*4, stream);
  hipMemsetAsync(menc, 0, BB*4, stream);     // enc-space 0 < every finite float's encoding
  hipMemsetAsync(denom, 0, BB*4, stream);
  hipMemsetAsync(out, 0, (size_t)BB*CC*4, stream);

  qmlp_k<<<BB, 256, 0, stream>>>(u, Wq1, bq1, Wq2, bq2, q);
  wk_k<<<dim3(256,2), 256, 0, stream>>>(Wn1, Wn2, Wk1, Wk2);

  const int gblocks = (NN + 127)/128;   // 3907
  mlp_gemm<1><<<gblocks, 512, 0, stream>>>(x, nullptr, Wk1, bn1, hws,
                                           nullptr, nullptr, nullptr);
  mlp_gemm<2><<<gblocks, 512, 0, stream>>>(nullptr, hws, Wk2, bn2, hws,
                                           q, batch, gate);

  segmax_k<<<(NN+511)/512, 512, 0, stream>>>(gate, batch, menc);
  expden_k<<<(NN+511)/512, 512, 0, stream>>>(gate, batch, menc, denom);
  pool_k<<<2048, 256, 0, stream>>>(hws, gate, denom, batch, out);
}